// Round 2
// baseline (555.498 us; speedup 1.0000x reference)
//
#include <hip/hip_runtime.h>
#include <hip/hip_bf16.h>

#define B_  64
#define R_  512
#define M_  256
#define A_  256
#define L_  4096
#define NT_ 32     // L-tiles per batch
#define TR_ 128    // rows per block

typedef float    f32x4 __attribute__((ext_vector_type(4)));
typedef _Float16 f16x8 __attribute__((ext_vector_type(8)));

// ---------------- kernel 0: Ua -> fp16 ----------------
__global__ __launch_bounds__(256) void k_prep(const float* __restrict__ Ua,
                                              _Float16* __restrict__ Ua16) {
  int idx = (blockIdx.x * 256 + threadIdx.x) * 4;
  f32x4 v = *(const f32x4*)(Ua + idx);
  Ua16[idx + 0] = (_Float16)v.x;
  Ua16[idx + 1] = (_Float16)v.y;
  Ua16[idx + 2] = (_Float16)v.z;
  Ua16[idx + 3] = (_Float16)v.w;
}

// ---------------- kernel 1: q = h @ Wa^T + ba ----------------
__global__ __launch_bounds__(256) void k_q(const float* __restrict__ h,
                                           const float* __restrict__ Wa,
                                           const float* __restrict__ ba,
                                           float* __restrict__ q) {
  int b = blockIdx.x;
  int tid = threadIdx.x;
  int wv = tid >> 6, lane = tid & 63;
  const f32x4* hp = (const f32x4*)(h + (size_t)b * R_ + lane * 8);
  f32x4 h0 = hp[0], h1 = hp[1];
#pragma unroll 4
  for (int i = 0; i < 64; ++i) {
    int a = wv * 64 + i;
    const f32x4* wp = (const f32x4*)(Wa + (size_t)a * R_ + lane * 8);
    f32x4 w0 = wp[0], w1 = wp[1];
    f32x4 pr = h0 * w0 + h1 * w1;
    float p = (pr.x + pr.y) + (pr.z + pr.w);
#pragma unroll
    for (int m = 1; m < 64; m <<= 1) p += __shfl_xor(p, m);
    if (lane == 0) q[b * A_ + a] = p + ba[a];
  }
}

// ---------------- kernel 2: single pass over fv ----------------
// e = tanh(q + fv@Ua^T) @ w  -> block-local online softmax ->
// partial (mx, sum, acc[256]) per 128-row block.
// fv rows live as fp16 A-fragments in registers; B-fragments read directly
// from global Ua16 (L1/L2-resident, exact MFMA B layout, no LDS staging).
__global__ __launch_bounds__(256) void k_main(const float* __restrict__ fv,
                                              const _Float16* __restrict__ Ua16,
                                              const float* __restrict__ q,
                                              const float* __restrict__ w,
                                              float* __restrict__ blkmax,
                                              float* __restrict__ blksum,
                                              float* __restrict__ blkacc) {
  __shared__ float sq[A_];
  __shared__ float sw[A_];
  __shared__ float sE[TR_];
  __shared__ float sRed[8];
  __shared__ float sAcc[4][M_];
  int tid = threadIdx.x;
  int b  = blockIdx.x >> 5;
  int l0 = (blockIdx.x & 31) * TR_;
  int wv = tid >> 6, lane = tid & 63;
  int quad = lane >> 4, l16 = lane & 15;

  sq[tid] = q[b * A_ + tid];
  sw[tid] = w[tid];

  // A fragments: A[m=lane&15][k=quad*8+j]; rows = l0 + wv*32 + rs*16 + l16
  f16x8 afrag[2][8];
#pragma unroll
  for (int rs = 0; rs < 2; ++rs) {
    const float* rowp = fv + ((size_t)b * L_ + (size_t)(l0 + wv * 32 + rs * 16 + l16)) * M_ + quad * 8;
#pragma unroll
    for (int s = 0; s < 8; ++s) {
      f32x4 x = *(const f32x4*)(rowp + s * 32);
      f32x4 y = *(const f32x4*)(rowp + s * 32 + 4);
      f16x8 f;
      f[0] = (_Float16)x.x; f[1] = (_Float16)x.y; f[2] = (_Float16)x.z; f[3] = (_Float16)x.w;
      f[4] = (_Float16)y.x; f[5] = (_Float16)y.y; f[6] = (_Float16)y.z; f[7] = (_Float16)y.w;
      afrag[rs][s] = f;
    }
  }
  __syncthreads();   // sq/sw visible

  float eacc[2][4] = {{0.f, 0.f, 0.f, 0.f}, {0.f, 0.f, 0.f, 0.f}};

#pragma unroll 4
  for (int t = 0; t < 16; ++t) {
    f32x4 acc0 = 0.f, acc1 = 0.f;
    // B[k=quad*8+j + s*32][n=l16] = Ua16[a = t*16+l16][m] — contiguous 16B
    const f16x8* bp = (const f16x8*)(Ua16 + ((size_t)(t * 16 + l16) << 8) + quad * 8);
#pragma unroll
    for (int s = 0; s < 8; ++s) {
      f16x8 bf = bp[s * 4];
      acc0 = __builtin_amdgcn_mfma_f32_16x16x32_f16(afrag[0][s], bf, acc0, 0, 0, 0);
      acc1 = __builtin_amdgcn_mfma_f32_16x16x32_f16(afrag[1][s], bf, acc1, 0, 0, 0);
    }
    // epilogue: a = t*16 + l16; C/D: col=l16, row=quad*4+i
    float qc = sq[t * 16 + l16], wc = sw[t * 16 + l16];
#pragma unroll
    for (int i = 0; i < 4; ++i) {
      float x0 = qc + acc0[i];
      float e0 = __expf(2.0f * x0);
      eacc[0][i] += (1.0f - 2.0f * __builtin_amdgcn_rcpf(e0 + 1.0f)) * wc;
      float x1 = qc + acc1[i];
      float e1 = __expf(2.0f * x1);
      eacc[1][i] += (1.0f - 2.0f * __builtin_amdgcn_rcpf(e1 + 1.0f)) * wc;
    }
  }

  // reduce eacc over the 16 column-lanes -> e rows into LDS
#pragma unroll
  for (int rs = 0; rs < 2; ++rs)
#pragma unroll
    for (int i = 0; i < 4; ++i) {
      float v = eacc[rs][i];
      v += __shfl_xor(v, 1); v += __shfl_xor(v, 2);
      v += __shfl_xor(v, 4); v += __shfl_xor(v, 8);
      if (l16 == 0) sE[wv * 32 + rs * 16 + quad * 4 + i] = v;
    }
  __syncthreads();

  // block max over 128 e values
  float m = (tid < TR_) ? sE[tid] : -1e30f;
#pragma unroll
  for (int k = 1; k < 64; k <<= 1) m = fmaxf(m, __shfl_xor(m, k));
  if (lane == 0) sRed[wv] = m;
  __syncthreads();
  float mx = fmaxf(fmaxf(sRed[0], sRed[1]), fmaxf(sRed[2], sRed[3]));

  // p for this thread's two rows
  float p0 = __expf(sE[wv * 32 + l16] - mx);
  float p1 = __expf(sE[wv * 32 + 16 + l16] - mx);

  // block sum of p (each row counted once: quad==0)
  float ps = (quad == 0) ? (p0 + p1) : 0.f;
#pragma unroll
  for (int k = 1; k < 64; k <<= 1) ps += __shfl_xor(ps, k);
  if (lane == 0) sRed[4 + wv] = ps;

  // ctx partial: col c = s*32 + quad*8 + j; sum over this wave's 32 rows
#pragma unroll
  for (int s = 0; s < 8; ++s) {
    float c[8];
#pragma unroll
    for (int j = 0; j < 8; ++j)
      c[j] = p0 * (float)afrag[0][s][j] + p1 * (float)afrag[1][s][j];
#pragma unroll
    for (int k = 1; k < 16; k <<= 1) {
#pragma unroll
      for (int j = 0; j < 8; ++j) c[j] += __shfl_xor(c[j], k);
    }
    if (l16 == 0) {
#pragma unroll
      for (int j = 0; j < 8; ++j) sAcc[wv][s * 32 + quad * 8 + j] = c[j];
    }
  }
  __syncthreads();

  float colsum = (sAcc[0][tid] + sAcc[1][tid]) + (sAcc[2][tid] + sAcc[3][tid]);
  blkacc[(size_t)blockIdx.x * M_ + tid] = colsum;
  if (tid == 0) {
    blkmax[blockIdx.x] = mx;
    blksum[blockIdx.x] = (sRed[4] + sRed[5]) + (sRed[6] + sRed[7]);
  }
}

// ---------------- kernel 3: combine 32 partials per batch ----------------
__global__ __launch_bounds__(256) void k_fin(const float* __restrict__ blkmax,
                                             const float* __restrict__ blksum,
                                             const float* __restrict__ blkacc,
                                             float* __restrict__ out) {
  __shared__ float sSc[NT_];
  int b = blockIdx.x, t = threadIdx.x;
  float M = -1e30f;
#pragma unroll
  for (int i = 0; i < NT_; ++i) M = fmaxf(M, blkmax[b * NT_ + i]);
  if (t < NT_) sSc[t] = __expf(blkmax[b * NT_ + t] - M);
  __syncthreads();
  float acc = 0.f, S = 0.f;
#pragma unroll 4
  for (int i = 0; i < NT_; ++i) {
    float sc = sSc[i];
    S += blksum[b * NT_ + i] * sc;
    acc += blkacc[(size_t)(b * NT_ + i) * M_ + t] * sc;
  }
  out[b * M_ + t] = acc / S;
}

extern "C" void kernel_launch(void* const* d_in, const int* in_sizes, int n_in,
                              void* d_out, int out_size, void* d_ws, size_t ws_size,
                              hipStream_t stream) {
  const float* h  = (const float*)d_in[0];   // [64, 512]
  const float* fv = (const float*)d_in[1];   // [64, 4096, 256]
  const float* Wa = (const float*)d_in[2];   // [256, 512]
  const float* Ua = (const float*)d_in[3];   // [256, 256]
  const float* w  = (const float*)d_in[4];   // [256, 1]
  const float* ba = (const float*)d_in[5];   // [1, 256]
  float* out = (float*)d_out;                // [64, 256]

  char* ws = (char*)d_ws;
  float*    q      = (float*)(ws);                    // 64*256*4    = 64 KB
  _Float16* Ua16   = (_Float16*)(ws + 65536);         // 256*256*2   = 128 KB
  float*    blkmax = (float*)(ws + 196608);           // 2048*4      = 8 KB
  float*    blksum = (float*)(ws + 204800);           // 2048*4      = 8 KB
  float*    blkacc = (float*)(ws + 212992);           // 2048*256*4  = 2 MB

  k_prep<<<dim3(64), dim3(256), 0, stream>>>(Ua, Ua16);
  k_q<<<dim3(B_), dim3(256), 0, stream>>>(h, Wa, ba, q);
  k_main<<<dim3(B_ * NT_), dim3(256), 0, stream>>>(fv, Ua16, q, w, blkmax, blksum, blkacc);
  k_fin<<<dim3(B_), dim3(256), 0, stream>>>(blkmax, blksum, blkacc, out);
}

// Round 3
// 466.074 us; speedup vs baseline: 1.1919x; 1.1919x over previous
//
#include <hip/hip_runtime.h>
#include <hip/hip_bf16.h>

#define B_  64
#define R_  512
#define M_  256
#define A_  256
#define L_  4096
#define TR_ 256            // rows per block (64 per wave)
#define NT2_ (L_ / TR_)    // 16 tiles per batch

typedef float    f32x4  __attribute__((ext_vector_type(4)));
typedef _Float16 f16x8  __attribute__((ext_vector_type(8)));
typedef _Float16 f16x4  __attribute__((ext_vector_type(4)));

// ---------------- kernel 0: Ua -> fp16, swizzled into MFMA B-fragment order ----
// UaSw half-index: ((t*8+s)*64 + l16*4 + quad)*8 + j
//   where a = t*16+l16 (A-row), m = s*32+quad*8+j (feature col).
// Result: the B-frag load for (t,s) is 64 lanes x 16B CONTIGUOUS (1 KB).
__global__ __launch_bounds__(256) void k_prep(const float* __restrict__ Ua,
                                              _Float16* __restrict__ UaSw) {
  int gid = blockIdx.x * 256 + threadIdx.x;   // 16384 threads
  int a  = gid >> 6;
  int m0 = (gid & 63) * 4;                     // j = m0&7 in {0,4}
  f32x4 v = *(const f32x4*)(Ua + (size_t)a * M_ + m0);
  int t = a >> 4, l16 = a & 15;
  int s = m0 >> 5, quad = (m0 >> 3) & 3, j = m0 & 7;
  size_t idx = ((size_t)((t * 8 + s) * 64 + l16 * 4 + quad)) * 8 + j;
  f16x4 h;
  h[0] = (_Float16)v.x; h[1] = (_Float16)v.y;
  h[2] = (_Float16)v.z; h[3] = (_Float16)v.w;
  *(f16x4*)(UaSw + idx) = h;
}

// ---------------- kernel 1: q = h @ Wa^T + ba ----------------
__global__ __launch_bounds__(256) void k_q(const float* __restrict__ h,
                                           const float* __restrict__ Wa,
                                           const float* __restrict__ ba,
                                           float* __restrict__ q) {
  int b = blockIdx.x;
  int tid = threadIdx.x;
  int wv = tid >> 6, lane = tid & 63;
  const f32x4* hp = (const f32x4*)(h + (size_t)b * R_ + lane * 8);
  f32x4 h0 = hp[0], h1 = hp[1];
#pragma unroll 4
  for (int i = 0; i < 64; ++i) {
    int a = wv * 64 + i;
    const f32x4* wp = (const f32x4*)(Wa + (size_t)a * R_ + lane * 8);
    f32x4 w0 = wp[0], w1 = wp[1];
    f32x4 pr = h0 * w0 + h1 * w1;
    float p = (pr.x + pr.y) + (pr.z + pr.w);
#pragma unroll
    for (int m = 1; m < 64; m <<= 1) p += __shfl_xor(p, m);
    if (lane == 0) q[b * A_ + a] = p + ba[a];
  }
}

// ---------------- kernel 2: single pass over fv ----------------
// Per block: 256 rows (64/wave). All global loads are wave-contiguous:
//   fv:  one row (1 KB) per instruction, lane i -> 16B chunk i
//   Ua:  swizzled frag order, 1 KB per (t,s)
// fv rows go through a wave-private LDS region (no barriers) to be
// re-read as MFMA A-fragments (b128, conflict-free), held in regs for all t.
__global__ __launch_bounds__(256, 2) void k_main(const float* __restrict__ fv,
                                                 const _Float16* __restrict__ UaSw,
                                                 const float* __restrict__ q,
                                                 const float* __restrict__ w,
                                                 float* __restrict__ blkmax,
                                                 float* __restrict__ blksum,
                                                 float* __restrict__ blkacc) {
  __shared__ __align__(16) _Float16 sA[4][4096];  // 8 KB per wave
  __shared__ float sq[A_];
  __shared__ float sw[A_];
  __shared__ float sE[TR_];
  __shared__ float sRed[8];
  __shared__ float sAcc[4][M_];
  int tid = threadIdx.x;
  int b  = blockIdx.x >> 4;
  int l0 = (blockIdx.x & 15) * TR_;
  int wv = tid >> 6, lane = tid & 63;
  int quad = lane >> 4, l16 = lane & 15;

  sq[tid] = q[b * A_ + tid];
  sw[tid] = w[tid];

  // write-side swizzle constants for this lane (m0 = lane*4)
  int s_w  = lane >> 3;
  int qd_w = (lane >> 1) & 3;
  int jh_w = (lane & 1) * 4;
  _Float16* wbase = &sA[wv][0];

  // A fragments for 4 chunks of 16 rows each: afrag[c][s]
  f16x8 afrag[4][8];
#pragma unroll
  for (int c = 0; c < 4; ++c) {
    const float* rowp = fv + ((size_t)b * L_ + (size_t)(l0 + wv * 64 + c * 16)) * M_ + lane * 4;
    // stage 16 rows: coalesced 1KB loads -> fp16 -> wave-private LDS (swizzled)
#pragma unroll
    for (int i = 0; i < 16; ++i) {
      f32x4 v = *(const f32x4*)(rowp + (size_t)i * M_);
      f16x4 h;
      h[0] = (_Float16)v.x; h[1] = (_Float16)v.y;
      h[2] = (_Float16)v.z; h[3] = (_Float16)v.w;
      *(f16x4*)(wbase + s_w * 512 + (i * 4 + qd_w) * 8 + jh_w) = h;
    }
    // read back as A-fragments: A[m=l16][k=quad*8+j], 16B per (s)
#pragma unroll
    for (int s = 0; s < 8; ++s)
      afrag[c][s] = *(const f16x8*)(wbase + s * 512 + (l16 * 4 + quad) * 8);
  }
  __syncthreads();   // sq/sw visible

  float eacc[4][4] = {{0,0,0,0},{0,0,0,0},{0,0,0,0},{0,0,0,0}};

#pragma unroll 2
  for (int t = 0; t < 16; ++t) {
    f32x4 acc0 = 0.f, acc1 = 0.f, acc2 = 0.f, acc3 = 0.f;
    const f16x8* bp = (const f16x8*)(UaSw + ((size_t)(t * 8) * 64 + (l16 * 4 + quad)) * 8);
#pragma unroll
    for (int s = 0; s < 8; ++s) {
      f16x8 bf = bp[s * 64];   // contiguous 1 KB per (t,s) across the wave
      acc0 = __builtin_amdgcn_mfma_f32_16x16x32_f16(afrag[0][s], bf, acc0, 0, 0, 0);
      acc1 = __builtin_amdgcn_mfma_f32_16x16x32_f16(afrag[1][s], bf, acc1, 0, 0, 0);
      acc2 = __builtin_amdgcn_mfma_f32_16x16x32_f16(afrag[2][s], bf, acc2, 0, 0, 0);
      acc3 = __builtin_amdgcn_mfma_f32_16x16x32_f16(afrag[3][s], bf, acc3, 0, 0, 0);
    }
    float qc = sq[t * 16 + l16], wc = sw[t * 16 + l16];
#pragma unroll
    for (int i = 0; i < 4; ++i) {
      float x0 = qc + acc0[i];
      eacc[0][i] += (1.0f - 2.0f * __builtin_amdgcn_rcpf(__expf(2.0f * x0) + 1.0f)) * wc;
      float x1 = qc + acc1[i];
      eacc[1][i] += (1.0f - 2.0f * __builtin_amdgcn_rcpf(__expf(2.0f * x1) + 1.0f)) * wc;
      float x2 = qc + acc2[i];
      eacc[2][i] += (1.0f - 2.0f * __builtin_amdgcn_rcpf(__expf(2.0f * x2) + 1.0f)) * wc;
      float x3 = qc + acc3[i];
      eacc[3][i] += (1.0f - 2.0f * __builtin_amdgcn_rcpf(__expf(2.0f * x3) + 1.0f)) * wc;
    }
  }

  // reduce eacc over the 16 column-lanes -> e rows into LDS
#pragma unroll
  for (int c = 0; c < 4; ++c)
#pragma unroll
    for (int i = 0; i < 4; ++i) {
      float v = eacc[c][i];
      v += __shfl_xor(v, 1); v += __shfl_xor(v, 2);
      v += __shfl_xor(v, 4); v += __shfl_xor(v, 8);
      if (l16 == 0) sE[wv * 64 + c * 16 + quad * 4 + i] = v;
    }
  __syncthreads();

  // block max over 256 e values
  float m = sE[tid];
#pragma unroll
  for (int k = 1; k < 64; k <<= 1) m = fmaxf(m, __shfl_xor(m, k));
  if (lane == 0) sRed[wv] = m;
  __syncthreads();
  float mx = fmaxf(fmaxf(sRed[0], sRed[1]), fmaxf(sRed[2], sRed[3]));

  // p for this lane's 4 rows (c, l16)
  float p[4];
#pragma unroll
  for (int c = 0; c < 4; ++c) p[c] = __expf(sE[wv * 64 + c * 16 + l16] - mx);

  // block sum of p (each row counted once: quad==0)
  float ps = (quad == 0) ? ((p[0] + p[1]) + (p[2] + p[3])) : 0.f;
#pragma unroll
  for (int k = 1; k < 64; k <<= 1) ps += __shfl_xor(ps, k);
  if (lane == 0) sRed[4 + wv] = ps;

  // ctx partial: col = s*32 + quad*8 + j; sum over this wave's 64 rows
#pragma unroll
  for (int s = 0; s < 8; ++s) {
    float cj[8];
#pragma unroll
    for (int j = 0; j < 8; ++j)
      cj[j] = p[0] * (float)afrag[0][s][j] + p[1] * (float)afrag[1][s][j] +
              p[2] * (float)afrag[2][s][j] + p[3] * (float)afrag[3][s][j];
#pragma unroll
    for (int k = 1; k < 16; k <<= 1) {
#pragma unroll
      for (int j = 0; j < 8; ++j) cj[j] += __shfl_xor(cj[j], k);
    }
    if (l16 == 0) {
#pragma unroll
      for (int j = 0; j < 8; ++j) sAcc[wv][s * 32 + quad * 8 + j] = cj[j];
    }
  }
  __syncthreads();

  float colsum = (sAcc[0][tid] + sAcc[1][tid]) + (sAcc[2][tid] + sAcc[3][tid]);
  blkacc[(size_t)blockIdx.x * M_ + tid] = colsum;
  if (tid == 0) {
    blkmax[blockIdx.x] = mx;
    blksum[blockIdx.x] = (sRed[4] + sRed[5]) + (sRed[6] + sRed[7]);
  }
}

// ---------------- kernel 3: combine 16 partials per batch ----------------
__global__ __launch_bounds__(256) void k_fin(const float* __restrict__ blkmax,
                                             const float* __restrict__ blksum,
                                             const float* __restrict__ blkacc,
                                             float* __restrict__ out) {
  __shared__ float sSc[NT2_];
  int b = blockIdx.x, t = threadIdx.x;
  float M = -1e30f;
#pragma unroll
  for (int i = 0; i < NT2_; ++i) M = fmaxf(M, blkmax[b * NT2_ + i]);
  if (t < NT2_) sSc[t] = __expf(blkmax[b * NT2_ + t] - M);
  __syncthreads();
  float acc = 0.f, S = 0.f;
#pragma unroll 4
  for (int i = 0; i < NT2_; ++i) {
    float sc = sSc[i];
    S += blksum[b * NT2_ + i] * sc;
    acc += blkacc[(size_t)(b * NT2_ + i) * M_ + t] * sc;
  }
  out[b * M_ + t] = acc / S;
}

extern "C" void kernel_launch(void* const* d_in, const int* in_sizes, int n_in,
                              void* d_out, int out_size, void* d_ws, size_t ws_size,
                              hipStream_t stream) {
  const float* h  = (const float*)d_in[0];   // [64, 512]
  const float* fv = (const float*)d_in[1];   // [64, 4096, 256]
  const float* Wa = (const float*)d_in[2];   // [256, 512]
  const float* Ua = (const float*)d_in[3];   // [256, 256]
  const float* w  = (const float*)d_in[4];   // [256, 1]
  const float* ba = (const float*)d_in[5];   // [1, 256]
  float* out = (float*)d_out;                // [64, 256]

  char* ws = (char*)d_ws;
  float*    q      = (float*)(ws);                    // 64 KB
  _Float16* UaSw   = (_Float16*)(ws + 65536);         // 128 KB
  float*    blkmax = (float*)(ws + 196608);           // 4 KB
  float*    blksum = (float*)(ws + 200704);           // 4 KB
  float*    blkacc = (float*)(ws + 204800);           // 1 MB

  k_prep<<<dim3(64), dim3(256), 0, stream>>>(Ua, UaSw);
  k_q<<<dim3(B_), dim3(256), 0, stream>>>(h, Wa, ba, q);
  k_main<<<dim3(B_ * NT2_), dim3(256), 0, stream>>>(fv, UaSw, q, w, blkmax, blksum, blkacc);
  k_fin<<<dim3(B_), dim3(256), 0, stream>>>(blkmax, blksum, blkacc, out);
}